// Round 1
// baseline (472.525 us; speedup 1.0000x reference)
//
#include <hip/hip_runtime.h>

// ---------------------------------------------------------------------------
// 2-layer GCN + LayerNorm on MI355X.
// Structure per call (all on `stream`):
//   1. k_init:        deg=1.0 (self-loop), cnt=0
//   2. k_count:       deg[dst]+=ew (float atomic), cnt[dst]++ (int atomic)
//   3. k_dinv:        dinv = rsqrt(deg)          (deg >= 1 always)
//   4. scan (3 kernels): exclusive prefix sum of cnt -> row_ptr, row_off
//   5. k_fill:        CSR by dst: csr_src[], csr_norm[]=dinv[s]*ew*dinv[d]
//   6. k_gemm:        h1 = x @ W1                  [N,128]@[128,256]
//   7. k_agg1:        out1 = relu(b1 + dinv^2*h1[i] + sum norm*h1[src])
//   8. k_gemm:        h2 = out1 @ W2               [N,256]@[256,128] (reuses h buf)
//   9. k_agg2_ln:     d_out = LN(b2 + dinv^2*h2[i] + sum norm*h2[src])*gamma+beta
// ---------------------------------------------------------------------------

#define TPB 256

__global__ void k_init(float* deg, int* cnt, int N) {
  int i = blockIdx.x * TPB + threadIdx.x;
  if (i < N) { deg[i] = 1.0f; cnt[i] = 0; }
}

__global__ void k_count(const int* __restrict__ dst, const float* __restrict__ ew,
                        float* deg, int* cnt, int E) {
  int e = blockIdx.x * TPB + threadIdx.x;
  if (e < E) {
    int d = dst[e];
    atomicAdd(&deg[d], ew[e]);
    atomicAdd(&cnt[d], 1);
  }
}

__global__ void k_dinv(float* deg, int N) {
  int i = blockIdx.x * TPB + threadIdx.x;
  if (i < N) deg[i] = rsqrtf(deg[i]);   // deg >= 1 from self-loop
}

// ---- exclusive scan of cnt[N] (N <= 256*256) ------------------------------
__global__ void k_block_reduce(const int* __restrict__ cnt, int* bsum, int N) {
  __shared__ int sm[TPB];
  int i = blockIdx.x * TPB + threadIdx.x;
  sm[threadIdx.x] = (i < N) ? cnt[i] : 0;
  __syncthreads();
  for (int s = TPB / 2; s > 0; s >>= 1) {
    if (threadIdx.x < s) sm[threadIdx.x] += sm[threadIdx.x + s];
    __syncthreads();
  }
  if (threadIdx.x == 0) bsum[blockIdx.x] = sm[0];
}

__global__ void k_scan_bsums(const int* __restrict__ bsum, int* bscan, int nb) {
  __shared__ int sm[TPB];
  int t = threadIdx.x;
  int v = (t < nb) ? bsum[t] : 0;
  sm[t] = v;
  __syncthreads();
  for (int off = 1; off < TPB; off <<= 1) {
    int add = (t >= off) ? sm[t - off] : 0;
    __syncthreads();
    sm[t] += add;
    __syncthreads();
  }
  if (t < nb) bscan[t] = sm[t] - v;   // exclusive
}

__global__ void k_block_scan(const int* __restrict__ cnt, const int* __restrict__ bscan,
                             int* row_ptr, int* row_off, int N) {
  __shared__ int sm[TPB];
  int t = threadIdx.x;
  int i = blockIdx.x * TPB + t;
  int v = (i < N) ? cnt[i] : 0;
  sm[t] = v;
  __syncthreads();
  for (int off = 1; off < TPB; off <<= 1) {
    int add = (t >= off) ? sm[t - off] : 0;
    __syncthreads();
    sm[t] += add;
    __syncthreads();
  }
  if (i < N) {
    int rs = bscan[blockIdx.x] + sm[t] - v;
    row_ptr[i] = rs;
    row_off[i] = rs;
  }
}

__global__ void k_fill(const int* __restrict__ src, const int* __restrict__ dst,
                       const float* __restrict__ ew, const float* __restrict__ dinv,
                       int* row_off, int* __restrict__ csr_src,
                       float* __restrict__ csr_norm, int E) {
  int e = blockIdx.x * TPB + threadIdx.x;
  if (e < E) {
    int d = dst[e], s = src[e];
    int pos = atomicAdd(&row_off[d], 1);
    csr_src[pos]  = s;
    csr_norm[pos] = dinv[s] * ew[e] * dinv[d];
  }
}

// ---- fp32 tiled GEMM: C[M,NC] = A[M,K] @ B[K,NC]; NC % 64 == 0, K % 32 == 0
__global__ __launch_bounds__(256) void k_gemm(const float* __restrict__ A,
                                              const float* __restrict__ B,
                                              float* __restrict__ C,
                                              int M, int K, int NC) {
  __shared__ float AsT[32][64];   // transposed A tile: AsT[k][row]
  __shared__ float Bs[32][64];
  const int tid = threadIdx.x;
  const int tr = tid >> 4, tc = tid & 15;
  const int row0 = blockIdx.y * 64, col0 = blockIdx.x * 64;
  float acc[4][4] = {};
  for (int k0 = 0; k0 < K; k0 += 32) {
#pragma unroll
    for (int l = 0; l < 2; ++l) {   // A tile: 64x32 = 512 float4, 2 per thread
      int q = tid + l * 256;
      int r = q >> 3, c4 = (q & 7) << 2;
      int gr = row0 + r;
      float4 v = make_float4(0.f, 0.f, 0.f, 0.f);
      if (gr < M) v = *reinterpret_cast<const float4*>(A + (size_t)gr * K + k0 + c4);
      AsT[c4 + 0][r] = v.x; AsT[c4 + 1][r] = v.y;
      AsT[c4 + 2][r] = v.z; AsT[c4 + 3][r] = v.w;
    }
#pragma unroll
    for (int l = 0; l < 2; ++l) {   // B tile: 32x64
      int q = tid + l * 256;
      int r = q >> 4, c4 = (q & 15) << 2;
      *reinterpret_cast<float4*>(&Bs[r][c4]) =
          *reinterpret_cast<const float4*>(B + (size_t)(k0 + r) * NC + col0 + c4);
    }
    __syncthreads();
#pragma unroll
    for (int k = 0; k < 32; ++k) {
      float4 a = *reinterpret_cast<const float4*>(&AsT[k][tr << 2]);
      float4 b = *reinterpret_cast<const float4*>(&Bs[k][tc << 2]);
      acc[0][0] += a.x * b.x; acc[0][1] += a.x * b.y; acc[0][2] += a.x * b.z; acc[0][3] += a.x * b.w;
      acc[1][0] += a.y * b.x; acc[1][1] += a.y * b.y; acc[1][2] += a.y * b.z; acc[1][3] += a.y * b.w;
      acc[2][0] += a.z * b.x; acc[2][1] += a.z * b.y; acc[2][2] += a.z * b.z; acc[2][3] += a.z * b.w;
      acc[3][0] += a.w * b.x; acc[3][1] += a.w * b.y; acc[3][2] += a.w * b.z; acc[3][3] += a.w * b.w;
    }
    __syncthreads();
  }
#pragma unroll
  for (int i = 0; i < 4; ++i) {
    int r = row0 + (tr << 2) + i;
    if (r < M) {
      float4 o = make_float4(acc[i][0], acc[i][1], acc[i][2], acc[i][3]);
      *reinterpret_cast<float4*>(C + (size_t)r * NC + col0 + (tc << 2)) = o;
    }
  }
}

// ---- aggregation layer 1: F=256, one wave per node, fused bias + ReLU -----
__global__ __launch_bounds__(256) void k_agg1(
    const float* __restrict__ h, const float* __restrict__ dinv,
    const int* __restrict__ row_ptr, const int* __restrict__ cnt,
    const int* __restrict__ csr_src, const float* __restrict__ csr_norm,
    const float* __restrict__ b1, float* __restrict__ out, int N) {
  const int F = 256;
  int wid = threadIdx.x >> 6, lane = threadIdx.x & 63;
  int node = blockIdx.x * 4 + wid;
  if (node >= N) return;
  float di = dinv[node];
  float sw = di * di;
  float4 acc = *reinterpret_cast<const float4*>(b1 + (lane << 2));
  float4 hv = *reinterpret_cast<const float4*>(h + (size_t)node * F + (lane << 2));
  acc.x += sw * hv.x; acc.y += sw * hv.y; acc.z += sw * hv.z; acc.w += sw * hv.w;
  int s0 = row_ptr[node], n = cnt[node];
  for (int j = 0; j < n; ++j) {
    int s   = csr_src[s0 + j];
    float w = csr_norm[s0 + j];
    float4 v = *reinterpret_cast<const float4*>(h + (size_t)s * F + (lane << 2));
    acc.x += w * v.x; acc.y += w * v.y; acc.z += w * v.z; acc.w += w * v.w;
  }
  acc.x = fmaxf(acc.x, 0.f); acc.y = fmaxf(acc.y, 0.f);
  acc.z = fmaxf(acc.z, 0.f); acc.w = fmaxf(acc.w, 0.f);
  *reinterpret_cast<float4*>(out + (size_t)node * F + (lane << 2)) = acc;
}

// ---- aggregation layer 2 + fused LayerNorm: F=128, one wave per node ------
__global__ __launch_bounds__(256) void k_agg2_ln(
    const float* __restrict__ h, const float* __restrict__ dinv,
    const int* __restrict__ row_ptr, const int* __restrict__ cnt,
    const int* __restrict__ csr_src, const float* __restrict__ csr_norm,
    const float* __restrict__ b2, const float* __restrict__ gamma,
    const float* __restrict__ beta, float* __restrict__ out, int N) {
  const int F = 128;
  int wid = threadIdx.x >> 6, lane = threadIdx.x & 63;
  int node = blockIdx.x * 4 + wid;
  if (node >= N) return;
  float di = dinv[node];
  float sw = di * di;
  float2 acc = *reinterpret_cast<const float2*>(b2 + (lane << 1));
  float2 hv = *reinterpret_cast<const float2*>(h + (size_t)node * F + (lane << 1));
  acc.x += sw * hv.x; acc.y += sw * hv.y;
  int s0 = row_ptr[node], n = cnt[node];
  for (int j = 0; j < n; ++j) {
    int s   = csr_src[s0 + j];
    float w = csr_norm[s0 + j];
    float2 v = *reinterpret_cast<const float2*>(h + (size_t)s * F + (lane << 1));
    acc.x += w * v.x; acc.y += w * v.y;
  }
  // LayerNorm across the wave (128 values = 64 lanes x 2)
  float s  = acc.x + acc.y;
  float ss = acc.x * acc.x + acc.y * acc.y;
  for (int m = 32; m > 0; m >>= 1) {
    s  += __shfl_xor(s, m, 64);
    ss += __shfl_xor(ss, m, 64);
  }
  float mu  = s * (1.0f / 128.0f);
  float var = ss * (1.0f / 128.0f) - mu * mu;
  float inv = rsqrtf(var + 1e-5f);
  float2 g  = *reinterpret_cast<const float2*>(gamma + (lane << 1));
  float2 be = *reinterpret_cast<const float2*>(beta + (lane << 1));
  float2 o;
  o.x = (acc.x - mu) * inv * g.x + be.x;
  o.y = (acc.y - mu) * inv * g.y + be.y;
  *reinterpret_cast<float2*>(out + (size_t)node * F + (lane << 1)) = o;
}

extern "C" void kernel_launch(void* const* d_in, const int* in_sizes, int n_in,
                              void* d_out, int out_size, void* d_ws, size_t ws_size,
                              hipStream_t stream) {
  const float* x     = (const float*)d_in[0];
  const int*   ei    = (const int*)d_in[1];
  const float* ew    = (const float*)d_in[2];
  const float* W1    = (const float*)d_in[3];
  const float* b1    = (const float*)d_in[4];
  const float* W2    = (const float*)d_in[5];
  const float* b2    = (const float*)d_in[6];
  const float* gamma = (const float*)d_in[7];
  const float* beta  = (const float*)d_in[8];
  float* out = (float*)d_out;

  const int D = 128, H = 256;
  const int N = in_sizes[0] / D;       // 50000
  const int E = in_sizes[2];           // 800000
  const int* src = ei;
  const int* dst = ei + E;

  // workspace carve-up (256B aligned)
  char* p = (char*)d_ws;
  auto carve = [&](size_t bytes) -> void* {
    void* r = (void*)p;
    p += (bytes + 255) & ~(size_t)255;
    return r;
  };
  float* deg      = (float*)carve((size_t)N * 4);      // becomes dinv
  int*   cnt      = (int*)  carve((size_t)N * 4);
  int*   row_ptr  = (int*)  carve((size_t)N * 4);
  int*   row_off  = (int*)  carve((size_t)N * 4);
  int*   bsum     = (int*)  carve(TPB * 4);
  int*   bscan    = (int*)  carve(TPB * 4);
  int*   csr_src  = (int*)  carve((size_t)E * 4);
  float* csr_norm = (float*)carve((size_t)E * 4);
  float* h        = (float*)carve((size_t)N * H * 4);  // h1, later reused as h2
  float* out1     = (float*)carve((size_t)N * H * 4);

  const int gN = (N + TPB - 1) / TPB;   // 196
  const int gE = (E + TPB - 1) / TPB;

  k_init<<<gN, TPB, 0, stream>>>(deg, cnt, N);
  k_count<<<gE, TPB, 0, stream>>>(dst, ew, deg, cnt, E);
  k_dinv<<<gN, TPB, 0, stream>>>(deg, N);
  k_block_reduce<<<gN, TPB, 0, stream>>>(cnt, bsum, N);
  k_scan_bsums<<<1, TPB, 0, stream>>>(bsum, bscan, gN);
  k_block_scan<<<gN, TPB, 0, stream>>>(cnt, bscan, row_ptr, row_off, N);
  k_fill<<<gE, TPB, 0, stream>>>(src, dst, ew, deg, row_off, csr_src, csr_norm, E);

  // layer 1
  dim3 g1(H / 64, (N + 63) / 64);
  k_gemm<<<g1, TPB, 0, stream>>>(x, W1, h, N, D, H);
  k_agg1<<<(N + 3) / 4, TPB, 0, stream>>>(h, deg, row_ptr, cnt, csr_src, csr_norm,
                                          b1, out1, N);
  // layer 2 (h buffer reused for h2)
  dim3 g2(D / 64, (N + 63) / 64);
  k_gemm<<<g2, TPB, 0, stream>>>(out1, W2, h, N, H, D);
  k_agg2_ln<<<(N + 3) / 4, TPB, 0, stream>>>(h, deg, row_ptr, cnt, csr_src, csr_norm,
                                             b2, gamma, beta, out, N);
}

// Round 2
// 369.882 us; speedup vs baseline: 1.2775x; 1.2775x over previous
//
#include <hip/hip_runtime.h>

// ---------------------------------------------------------------------------
// 2-layer GCN + LayerNorm on MI355X.
//   GCN layer 1 computed aggregate-FIRST (associativity):
//     ax   = A_norm @ x            [N,128] gather  (was 256-wide: 2x bytes)
//     out1 = relu(ax @ W1 + b1)    [N,256] fused GEMM epilogue
//   GCN layer 2 transform-first (keeps gather at 128-wide):
//     h2   = out1 @ W2             [N,128]
//     out  = LN(b2 + A_norm @ h2) * gamma + beta   (fused agg+LN)
// CSR by dst built per call; entries packed int2{src, float_bits(norm)}.
// ---------------------------------------------------------------------------

#define TPB 256

__global__ void k_init(float* deg, int* cnt, int N) {
  int i = blockIdx.x * TPB + threadIdx.x;
  if (i < N) { deg[i] = 1.0f; cnt[i] = 0; }
}

__global__ void k_count(const int* __restrict__ dst, const float* __restrict__ ew,
                        float* deg, int* cnt, int E) {
  int e = blockIdx.x * TPB + threadIdx.x;
  if (e < E) {
    int d = dst[e];
    atomicAdd(&deg[d], ew[e]);
    atomicAdd(&cnt[d], 1);
  }
}

__global__ void k_dinv(float* deg, int N) {
  int i = blockIdx.x * TPB + threadIdx.x;
  if (i < N) deg[i] = rsqrtf(deg[i]);   // deg >= 1 from self-loop
}

// ---- exclusive scan of cnt[N] (N <= 256*256) ------------------------------
__global__ void k_block_reduce(const int* __restrict__ cnt, int* bsum, int N) {
  __shared__ int sm[TPB];
  int i = blockIdx.x * TPB + threadIdx.x;
  sm[threadIdx.x] = (i < N) ? cnt[i] : 0;
  __syncthreads();
  for (int s = TPB / 2; s > 0; s >>= 1) {
    if (threadIdx.x < s) sm[threadIdx.x] += sm[threadIdx.x + s];
    __syncthreads();
  }
  if (threadIdx.x == 0) bsum[blockIdx.x] = sm[0];
}

__global__ void k_scan_bsums(const int* __restrict__ bsum, int* bscan, int nb) {
  __shared__ int sm[TPB];
  int t = threadIdx.x;
  int v = (t < nb) ? bsum[t] : 0;
  sm[t] = v;
  __syncthreads();
  for (int off = 1; off < TPB; off <<= 1) {
    int add = (t >= off) ? sm[t - off] : 0;
    __syncthreads();
    sm[t] += add;
    __syncthreads();
  }
  if (t < nb) bscan[t] = sm[t] - v;   // exclusive
}

__global__ void k_block_scan(const int* __restrict__ cnt, const int* __restrict__ bscan,
                             int* row_ptr, int* row_off, int N) {
  __shared__ int sm[TPB];
  int t = threadIdx.x;
  int i = blockIdx.x * TPB + t;
  int v = (i < N) ? cnt[i] : 0;
  sm[t] = v;
  __syncthreads();
  for (int off = 1; off < TPB; off <<= 1) {
    int add = (t >= off) ? sm[t - off] : 0;
    __syncthreads();
    sm[t] += add;
    __syncthreads();
  }
  if (i < N) {
    int rs = bscan[blockIdx.x] + sm[t] - v;
    row_ptr[i] = rs;
    row_off[i] = rs;
  }
}

__global__ void k_fill(const int* __restrict__ src, const int* __restrict__ dst,
                       const float* __restrict__ ew, const float* __restrict__ dinv,
                       int* row_off, int2* __restrict__ csr, int E) {
  int e = blockIdx.x * TPB + threadIdx.x;
  if (e < E) {
    int d = dst[e], s = src[e];
    int pos = atomicAdd(&row_off[d], 1);
    float nrm = dinv[s] * ew[e] * dinv[d];
    csr[pos] = make_int2(s, __float_as_int(nrm));
  }
}

// ---- fp32 tiled GEMM: C[M,NC] = A[M,K] @ B[K,NC] (+bias, +relu) -----------
// NC % 64 == 0, K % 32 == 0
__global__ __launch_bounds__(256) void k_gemm(const float* __restrict__ A,
                                              const float* __restrict__ B,
                                              float* __restrict__ C,
                                              const float* __restrict__ bias,
                                              int relu, int M, int K, int NC) {
  __shared__ float AsT[32][64];   // transposed A tile: AsT[k][row]
  __shared__ float Bs[32][64];
  const int tid = threadIdx.x;
  const int tr = tid >> 4, tc = tid & 15;
  const int row0 = blockIdx.y * 64, col0 = blockIdx.x * 64;
  float acc[4][4] = {};
  for (int k0 = 0; k0 < K; k0 += 32) {
#pragma unroll
    for (int l = 0; l < 2; ++l) {   // A tile: 64x32 = 512 float4, 2 per thread
      int q = tid + l * 256;
      int r = q >> 3, c4 = (q & 7) << 2;
      int gr = row0 + r;
      float4 v = make_float4(0.f, 0.f, 0.f, 0.f);
      if (gr < M) v = *reinterpret_cast<const float4*>(A + (size_t)gr * K + k0 + c4);
      AsT[c4 + 0][r] = v.x; AsT[c4 + 1][r] = v.y;
      AsT[c4 + 2][r] = v.z; AsT[c4 + 3][r] = v.w;
    }
#pragma unroll
    for (int l = 0; l < 2; ++l) {   // B tile: 32x64
      int q = tid + l * 256;
      int r = q >> 4, c4 = (q & 15) << 2;
      *reinterpret_cast<float4*>(&Bs[r][c4]) =
          *reinterpret_cast<const float4*>(B + (size_t)(k0 + r) * NC + col0 + c4);
    }
    __syncthreads();
#pragma unroll
    for (int k = 0; k < 32; ++k) {
      float4 a = *reinterpret_cast<const float4*>(&AsT[k][tr << 2]);
      float4 b = *reinterpret_cast<const float4*>(&Bs[k][tc << 2]);
      acc[0][0] += a.x * b.x; acc[0][1] += a.x * b.y; acc[0][2] += a.x * b.z; acc[0][3] += a.x * b.w;
      acc[1][0] += a.y * b.x; acc[1][1] += a.y * b.y; acc[1][2] += a.y * b.z; acc[1][3] += a.y * b.w;
      acc[2][0] += a.z * b.x; acc[2][1] += a.z * b.y; acc[2][2] += a.z * b.z; acc[2][3] += a.z * b.w;
      acc[3][0] += a.w * b.x; acc[3][1] += a.w * b.y; acc[3][2] += a.w * b.z; acc[3][3] += a.w * b.w;
    }
    __syncthreads();
  }
  float4 bv = make_float4(0.f, 0.f, 0.f, 0.f);
  if (bias) bv = *reinterpret_cast<const float4*>(bias + col0 + (tc << 2));
#pragma unroll
  for (int i = 0; i < 4; ++i) {
    int r = row0 + (tr << 2) + i;
    if (r < M) {
      float4 o = make_float4(acc[i][0] + bv.x, acc[i][1] + bv.y,
                             acc[i][2] + bv.z, acc[i][3] + bv.w);
      if (relu) {
        o.x = fmaxf(o.x, 0.f); o.y = fmaxf(o.y, 0.f);
        o.z = fmaxf(o.z, 0.f); o.w = fmaxf(o.w, 0.f);
      }
      *reinterpret_cast<float4*>(C + (size_t)r * NC + col0 + (tc << 2)) = o;
    }
  }
}

// ---- aggregation, F=128, one wave per node: out = dinv^2*h[i] + sum n*h[s]
// (no bias/epilogue; used for layer 1 on x)
__global__ __launch_bounds__(256) void k_agg_x(
    const float* __restrict__ h, const float* __restrict__ dinv,
    const int* __restrict__ row_ptr, const int* __restrict__ cnt,
    const int2* __restrict__ csr, float* __restrict__ out, int N) {
  const int F = 128;
  int wid = threadIdx.x >> 6, lane = threadIdx.x & 63;
  int node = blockIdx.x * 4 + wid;
  if (node >= N) return;
  float di = dinv[node];
  float sw = di * di;
  int c2 = lane << 1;
  float2 hv = *reinterpret_cast<const float2*>(h + (size_t)node * F + c2);
  float2 acc = make_float2(sw * hv.x, sw * hv.y);
  const int2* cp = csr + row_ptr[node];
  int n = cnt[node];
  int j = 0;
  for (; j + 4 <= n; j += 4) {
    int2 e0 = cp[j], e1 = cp[j + 1], e2 = cp[j + 2], e3 = cp[j + 3];
    float2 v0 = *reinterpret_cast<const float2*>(h + (size_t)e0.x * F + c2);
    float2 v1 = *reinterpret_cast<const float2*>(h + (size_t)e1.x * F + c2);
    float2 v2 = *reinterpret_cast<const float2*>(h + (size_t)e2.x * F + c2);
    float2 v3 = *reinterpret_cast<const float2*>(h + (size_t)e3.x * F + c2);
    float w0 = __int_as_float(e0.y), w1 = __int_as_float(e1.y);
    float w2 = __int_as_float(e2.y), w3 = __int_as_float(e3.y);
    acc.x += w0 * v0.x + w1 * v1.x + w2 * v2.x + w3 * v3.x;
    acc.y += w0 * v0.y + w1 * v1.y + w2 * v2.y + w3 * v3.y;
  }
  for (; j < n; ++j) {
    int2 e = cp[j];
    float w = __int_as_float(e.y);
    float2 v = *reinterpret_cast<const float2*>(h + (size_t)e.x * F + c2);
    acc.x += w * v.x; acc.y += w * v.y;
  }
  *reinterpret_cast<float2*>(out + (size_t)node * F + c2) = acc;
}

// ---- aggregation layer 2 + fused bias + LayerNorm: F=128 ------------------
__global__ __launch_bounds__(256) void k_agg2_ln(
    const float* __restrict__ h, const float* __restrict__ dinv,
    const int* __restrict__ row_ptr, const int* __restrict__ cnt,
    const int2* __restrict__ csr, const float* __restrict__ b2,
    const float* __restrict__ gamma, const float* __restrict__ beta,
    float* __restrict__ out, int N) {
  const int F = 128;
  int wid = threadIdx.x >> 6, lane = threadIdx.x & 63;
  int node = blockIdx.x * 4 + wid;
  if (node >= N) return;
  float di = dinv[node];
  float sw = di * di;
  int c2 = lane << 1;
  float2 acc = *reinterpret_cast<const float2*>(b2 + c2);
  float2 hv = *reinterpret_cast<const float2*>(h + (size_t)node * F + c2);
  acc.x += sw * hv.x; acc.y += sw * hv.y;
  const int2* cp = csr + row_ptr[node];
  int n = cnt[node];
  int j = 0;
  for (; j + 4 <= n; j += 4) {
    int2 e0 = cp[j], e1 = cp[j + 1], e2 = cp[j + 2], e3 = cp[j + 3];
    float2 v0 = *reinterpret_cast<const float2*>(h + (size_t)e0.x * F + c2);
    float2 v1 = *reinterpret_cast<const float2*>(h + (size_t)e1.x * F + c2);
    float2 v2 = *reinterpret_cast<const float2*>(h + (size_t)e2.x * F + c2);
    float2 v3 = *reinterpret_cast<const float2*>(h + (size_t)e3.x * F + c2);
    float w0 = __int_as_float(e0.y), w1 = __int_as_float(e1.y);
    float w2 = __int_as_float(e2.y), w3 = __int_as_float(e3.y);
    acc.x += w0 * v0.x + w1 * v1.x + w2 * v2.x + w3 * v3.x;
    acc.y += w0 * v0.y + w1 * v1.y + w2 * v2.y + w3 * v3.y;
  }
  for (; j < n; ++j) {
    int2 e = cp[j];
    float w = __int_as_float(e.y);
    float2 v = *reinterpret_cast<const float2*>(h + (size_t)e.x * F + c2);
    acc.x += w * v.x; acc.y += w * v.y;
  }
  // LayerNorm across the wave (128 values = 64 lanes x 2)
  float s  = acc.x + acc.y;
  float ss = acc.x * acc.x + acc.y * acc.y;
  for (int m = 32; m > 0; m >>= 1) {
    s  += __shfl_xor(s, m, 64);
    ss += __shfl_xor(ss, m, 64);
  }
  float mu  = s * (1.0f / 128.0f);
  float var = ss * (1.0f / 128.0f) - mu * mu;
  float inv = rsqrtf(var + 1e-5f);
  float2 g  = *reinterpret_cast<const float2*>(gamma + c2);
  float2 be = *reinterpret_cast<const float2*>(beta + c2);
  float2 o;
  o.x = (acc.x - mu) * inv * g.x + be.x;
  o.y = (acc.y - mu) * inv * g.y + be.y;
  *reinterpret_cast<float2*>(out + (size_t)node * F + c2) = o;
}

extern "C" void kernel_launch(void* const* d_in, const int* in_sizes, int n_in,
                              void* d_out, int out_size, void* d_ws, size_t ws_size,
                              hipStream_t stream) {
  const float* x     = (const float*)d_in[0];
  const int*   ei    = (const int*)d_in[1];
  const float* ew    = (const float*)d_in[2];
  const float* W1    = (const float*)d_in[3];
  const float* b1    = (const float*)d_in[4];
  const float* W2    = (const float*)d_in[5];
  const float* b2    = (const float*)d_in[6];
  const float* gamma = (const float*)d_in[7];
  const float* beta  = (const float*)d_in[8];
  float* out = (float*)d_out;

  const int D = 128, H = 256;
  const int N = in_sizes[0] / D;       // 50000
  const int E = in_sizes[2];           // 800000
  const int* src = ei;
  const int* dst = ei + E;

  // workspace carve-up (256B aligned)
  char* p = (char*)d_ws;
  auto carve = [&](size_t bytes) -> void* {
    void* r = (void*)p;
    p += (bytes + 255) & ~(size_t)255;
    return r;
  };
  float* deg     = (float*)carve((size_t)N * 4);      // becomes dinv
  int*   cnt     = (int*)  carve((size_t)N * 4);
  int*   row_ptr = (int*)  carve((size_t)N * 4);
  int*   row_off = (int*)  carve((size_t)N * 4);
  int*   bsum    = (int*)  carve(TPB * 4);
  int*   bscan   = (int*)  carve(TPB * 4);
  int2*  csr     = (int2*) carve((size_t)E * 8);
  float* ax      = (float*)carve((size_t)N * D * 4);  // A_norm @ x   [N,128]
  float* out1    = (float*)carve((size_t)N * H * 4);  // relu(ax@W1+b1) [N,256]
  float* h2      = (float*)carve((size_t)N * D * 4);  // out1@W2      [N,128]

  const int gN = (N + TPB - 1) / TPB;   // 196
  const int gE = (E + TPB - 1) / TPB;

  k_init<<<gN, TPB, 0, stream>>>(deg, cnt, N);
  k_count<<<gE, TPB, 0, stream>>>(dst, ew, deg, cnt, E);
  k_dinv<<<gN, TPB, 0, stream>>>(deg, N);
  k_block_reduce<<<gN, TPB, 0, stream>>>(cnt, bsum, N);
  k_scan_bsums<<<1, TPB, 0, stream>>>(bsum, bscan, gN);
  k_block_scan<<<gN, TPB, 0, stream>>>(cnt, bscan, row_ptr, row_off, N);
  k_fill<<<gE, TPB, 0, stream>>>(src, dst, ew, deg, row_off, csr, E);

  // layer 1: aggregate-first, then fused GEMM+bias+relu
  k_agg_x<<<(N + 3) / 4, TPB, 0, stream>>>(x, deg, row_ptr, cnt, csr, ax, N);
  dim3 g1(H / 64, (N + 63) / 64);
  k_gemm<<<g1, TPB, 0, stream>>>(ax, W1, out1, b1, 1, N, D, H);

  // layer 2: transform-first, then fused agg+bias+LN
  dim3 g2(D / 64, (N + 63) / 64);
  k_gemm<<<g2, TPB, 0, stream>>>(out1, W2, h2, nullptr, 0, N, H, D);
  k_agg2_ln<<<(N + 3) / 4, TPB, 0, stream>>>(h2, deg, row_ptr, cnt, csr,
                                             b2, gamma, beta, out, N);
}

// Round 3
// 337.153 us; speedup vs baseline: 1.4015x; 1.0971x over previous
//
#include <hip/hip_runtime.h>

// ---------------------------------------------------------------------------
// 2-layer GCN + LayerNorm on MI355X.
//   Graph build (per call, deterministic) via per-dst LINKED LIST:
//     k_link:      next[e] = atomicExch(&head[dst[e]], e)   (1 atomic/edge)
//     k_walk_deg:  per node: walk list, deg = 1 + sum ew -> dinv, cnt (no atomics)
//     scan:        exclusive prefix sum of cnt -> row_ptr
//     k_walk_fill: per node: walk list again, append {src, norm} to own row
//   Layer 1 aggregate-first (associativity):
//     ax   = A_norm @ x            [N,128] gather
//     out1 = relu(ax @ W1 + b1)    fused GEMM epilogue
//   Layer 2 transform-first:
//     h2   = out1 @ W2             [N,128]
//     out  = LN(b2 + A_norm @ h2) * gamma + beta   (fused agg+LN)
// ---------------------------------------------------------------------------

#define TPB 256

__global__ void k_head_init(int* head, int N) {
  int i = blockIdx.x * TPB + threadIdx.x;
  if (i < N) head[i] = -1;
}

__global__ void k_link(const int* __restrict__ dst, int* head,
                       int* __restrict__ next, int E) {
  int e = blockIdx.x * TPB + threadIdx.x;
  if (e < E) next[e] = atomicExch(&head[dst[e]], e);
}

// thread-per-node: walk list, deg = 1 + sum(ew), dinv = rsqrt(deg), cnt = len
__global__ void k_walk_deg(const int* __restrict__ head, const int* __restrict__ next,
                           const float* __restrict__ ew, float* __restrict__ dinv,
                           int* __restrict__ cnt, int N) {
  int i = blockIdx.x * TPB + threadIdx.x;
  if (i >= N) return;
  float d = 1.0f;   // self-loop weight
  int c = 0;
  int h = head[i];
  while (h >= 0) {
    d += ew[h];
    ++c;
    h = next[h];
  }
  dinv[i] = rsqrtf(d);
  cnt[i] = c;
}

// ---- exclusive scan of cnt[N] (N <= 256*256) ------------------------------
__global__ void k_block_reduce(const int* __restrict__ cnt, int* bsum, int N) {
  __shared__ int sm[TPB];
  int i = blockIdx.x * TPB + threadIdx.x;
  sm[threadIdx.x] = (i < N) ? cnt[i] : 0;
  __syncthreads();
  for (int s = TPB / 2; s > 0; s >>= 1) {
    if (threadIdx.x < s) sm[threadIdx.x] += sm[threadIdx.x + s];
    __syncthreads();
  }
  if (threadIdx.x == 0) bsum[blockIdx.x] = sm[0];
}

__global__ void k_scan_bsums(const int* __restrict__ bsum, int* bscan, int nb) {
  __shared__ int sm[TPB];
  int t = threadIdx.x;
  int v = (t < nb) ? bsum[t] : 0;
  sm[t] = v;
  __syncthreads();
  for (int off = 1; off < TPB; off <<= 1) {
    int add = (t >= off) ? sm[t - off] : 0;
    __syncthreads();
    sm[t] += add;
    __syncthreads();
  }
  if (t < nb) bscan[t] = sm[t] - v;   // exclusive
}

__global__ void k_block_scan(const int* __restrict__ cnt, const int* __restrict__ bscan,
                             int* row_ptr, int N) {
  __shared__ int sm[TPB];
  int t = threadIdx.x;
  int i = blockIdx.x * TPB + t;
  int v = (i < N) ? cnt[i] : 0;
  sm[t] = v;
  __syncthreads();
  for (int off = 1; off < TPB; off <<= 1) {
    int add = (t >= off) ? sm[t - off] : 0;
    __syncthreads();
    sm[t] += add;
    __syncthreads();
  }
  if (i < N) row_ptr[i] = bscan[blockIdx.x] + sm[t] - v;
}

// thread-per-node: walk list again, write {src, norm} contiguously to own row
__global__ void k_walk_fill(const int* __restrict__ head, const int* __restrict__ next,
                            const int* __restrict__ src, const float* __restrict__ ew,
                            const float* __restrict__ dinv,
                            const int* __restrict__ row_ptr,
                            int2* __restrict__ csr, int N) {
  int i = blockIdx.x * TPB + threadIdx.x;
  if (i >= N) return;
  float di = dinv[i];
  int pos = row_ptr[i];
  int h = head[i];
  while (h >= 0) {
    int s = src[h];
    float nrm = dinv[s] * ew[h] * di;
    csr[pos++] = make_int2(s, __float_as_int(nrm));
    h = next[h];
  }
}

// ---- fp32 tiled GEMM: C[M,NC] = A[M,K] @ B[K,NC] (+bias, +relu) -----------
// NC % 64 == 0, K % 32 == 0
__global__ __launch_bounds__(256) void k_gemm(const float* __restrict__ A,
                                              const float* __restrict__ B,
                                              float* __restrict__ C,
                                              const float* __restrict__ bias,
                                              int relu, int M, int K, int NC) {
  __shared__ float AsT[32][64];   // transposed A tile: AsT[k][row]
  __shared__ float Bs[32][64];
  const int tid = threadIdx.x;
  const int tr = tid >> 4, tc = tid & 15;
  const int row0 = blockIdx.y * 64, col0 = blockIdx.x * 64;
  float acc[4][4] = {};
  for (int k0 = 0; k0 < K; k0 += 32) {
#pragma unroll
    for (int l = 0; l < 2; ++l) {   // A tile: 64x32 = 512 float4, 2 per thread
      int q = tid + l * 256;
      int r = q >> 3, c4 = (q & 7) << 2;
      int gr = row0 + r;
      float4 v = make_float4(0.f, 0.f, 0.f, 0.f);
      if (gr < M) v = *reinterpret_cast<const float4*>(A + (size_t)gr * K + k0 + c4);
      AsT[c4 + 0][r] = v.x; AsT[c4 + 1][r] = v.y;
      AsT[c4 + 2][r] = v.z; AsT[c4 + 3][r] = v.w;
    }
#pragma unroll
    for (int l = 0; l < 2; ++l) {   // B tile: 32x64
      int q = tid + l * 256;
      int r = q >> 4, c4 = (q & 15) << 2;
      *reinterpret_cast<float4*>(&Bs[r][c4]) =
          *reinterpret_cast<const float4*>(B + (size_t)(k0 + r) * NC + col0 + c4);
    }
    __syncthreads();
#pragma unroll
    for (int k = 0; k < 32; ++k) {
      float4 a = *reinterpret_cast<const float4*>(&AsT[k][tr << 2]);
      float4 b = *reinterpret_cast<const float4*>(&Bs[k][tc << 2]);
      acc[0][0] += a.x * b.x; acc[0][1] += a.x * b.y; acc[0][2] += a.x * b.z; acc[0][3] += a.x * b.w;
      acc[1][0] += a.y * b.x; acc[1][1] += a.y * b.y; acc[1][2] += a.y * b.z; acc[1][3] += a.y * b.w;
      acc[2][0] += a.z * b.x; acc[2][1] += a.z * b.y; acc[2][2] += a.z * b.z; acc[2][3] += a.z * b.w;
      acc[3][0] += a.w * b.x; acc[3][1] += a.w * b.y; acc[3][2] += a.w * b.z; acc[3][3] += a.w * b.w;
    }
    __syncthreads();
  }
  float4 bv = make_float4(0.f, 0.f, 0.f, 0.f);
  if (bias) bv = *reinterpret_cast<const float4*>(bias + col0 + (tc << 2));
#pragma unroll
  for (int i = 0; i < 4; ++i) {
    int r = row0 + (tr << 2) + i;
    if (r < M) {
      float4 o = make_float4(acc[i][0] + bv.x, acc[i][1] + bv.y,
                             acc[i][2] + bv.z, acc[i][3] + bv.w);
      if (relu) {
        o.x = fmaxf(o.x, 0.f); o.y = fmaxf(o.y, 0.f);
        o.z = fmaxf(o.z, 0.f); o.w = fmaxf(o.w, 0.f);
      }
      *reinterpret_cast<float4*>(C + (size_t)r * NC + col0 + (tc << 2)) = o;
    }
  }
}

// ---- aggregation, F=128, one wave per node: out = dinv^2*h[i] + sum n*h[s]
__global__ __launch_bounds__(256) void k_agg_x(
    const float* __restrict__ h, const float* __restrict__ dinv,
    const int* __restrict__ row_ptr, const int* __restrict__ cnt,
    const int2* __restrict__ csr, float* __restrict__ out, int N) {
  const int F = 128;
  int wid = threadIdx.x >> 6, lane = threadIdx.x & 63;
  int node = blockIdx.x * 4 + wid;
  if (node >= N) return;
  float di = dinv[node];
  float sw = di * di;
  int c2 = lane << 1;
  float2 hv = *reinterpret_cast<const float2*>(h + (size_t)node * F + c2);
  float2 acc = make_float2(sw * hv.x, sw * hv.y);
  const int2* cp = csr + row_ptr[node];
  int n = cnt[node];
  int j = 0;
  for (; j + 4 <= n; j += 4) {
    int2 e0 = cp[j], e1 = cp[j + 1], e2 = cp[j + 2], e3 = cp[j + 3];
    float2 v0 = *reinterpret_cast<const float2*>(h + (size_t)e0.x * F + c2);
    float2 v1 = *reinterpret_cast<const float2*>(h + (size_t)e1.x * F + c2);
    float2 v2 = *reinterpret_cast<const float2*>(h + (size_t)e2.x * F + c2);
    float2 v3 = *reinterpret_cast<const float2*>(h + (size_t)e3.x * F + c2);
    float w0 = __int_as_float(e0.y), w1 = __int_as_float(e1.y);
    float w2 = __int_as_float(e2.y), w3 = __int_as_float(e3.y);
    acc.x += w0 * v0.x + w1 * v1.x + w2 * v2.x + w3 * v3.x;
    acc.y += w0 * v0.y + w1 * v1.y + w2 * v2.y + w3 * v3.y;
  }
  for (; j < n; ++j) {
    int2 e = cp[j];
    float w = __int_as_float(e.y);
    float2 v = *reinterpret_cast<const float2*>(h + (size_t)e.x * F + c2);
    acc.x += w * v.x; acc.y += w * v.y;
  }
  *reinterpret_cast<float2*>(out + (size_t)node * F + c2) = acc;
}

// ---- aggregation layer 2 + fused bias + LayerNorm: F=128 ------------------
__global__ __launch_bounds__(256) void k_agg2_ln(
    const float* __restrict__ h, const float* __restrict__ dinv,
    const int* __restrict__ row_ptr, const int* __restrict__ cnt,
    const int2* __restrict__ csr, const float* __restrict__ b2,
    const float* __restrict__ gamma, const float* __restrict__ beta,
    float* __restrict__ out, int N) {
  const int F = 128;
  int wid = threadIdx.x >> 6, lane = threadIdx.x & 63;
  int node = blockIdx.x * 4 + wid;
  if (node >= N) return;
  float di = dinv[node];
  float sw = di * di;
  int c2 = lane << 1;
  float2 acc = *reinterpret_cast<const float2*>(b2 + c2);
  float2 hv = *reinterpret_cast<const float2*>(h + (size_t)node * F + c2);
  acc.x += sw * hv.x; acc.y += sw * hv.y;
  const int2* cp = csr + row_ptr[node];
  int n = cnt[node];
  int j = 0;
  for (; j + 4 <= n; j += 4) {
    int2 e0 = cp[j], e1 = cp[j + 1], e2 = cp[j + 2], e3 = cp[j + 3];
    float2 v0 = *reinterpret_cast<const float2*>(h + (size_t)e0.x * F + c2);
    float2 v1 = *reinterpret_cast<const float2*>(h + (size_t)e1.x * F + c2);
    float2 v2 = *reinterpret_cast<const float2*>(h + (size_t)e2.x * F + c2);
    float2 v3 = *reinterpret_cast<const float2*>(h + (size_t)e3.x * F + c2);
    float w0 = __int_as_float(e0.y), w1 = __int_as_float(e1.y);
    float w2 = __int_as_float(e2.y), w3 = __int_as_float(e3.y);
    acc.x += w0 * v0.x + w1 * v1.x + w2 * v2.x + w3 * v3.x;
    acc.y += w0 * v0.y + w1 * v1.y + w2 * v2.y + w3 * v3.y;
  }
  for (; j < n; ++j) {
    int2 e = cp[j];
    float w = __int_as_float(e.y);
    float2 v = *reinterpret_cast<const float2*>(h + (size_t)e.x * F + c2);
    acc.x += w * v.x; acc.y += w * v.y;
  }
  // LayerNorm across the wave (128 values = 64 lanes x 2)
  float s  = acc.x + acc.y;
  float ss = acc.x * acc.x + acc.y * acc.y;
  for (int m = 32; m > 0; m >>= 1) {
    s  += __shfl_xor(s, m, 64);
    ss += __shfl_xor(ss, m, 64);
  }
  float mu  = s * (1.0f / 128.0f);
  float var = ss * (1.0f / 128.0f) - mu * mu;
  float inv = rsqrtf(var + 1e-5f);
  float2 g  = *reinterpret_cast<const float2*>(gamma + c2);
  float2 be = *reinterpret_cast<const float2*>(beta + c2);
  float2 o;
  o.x = (acc.x - mu) * inv * g.x + be.x;
  o.y = (acc.y - mu) * inv * g.y + be.y;
  *reinterpret_cast<float2*>(out + (size_t)node * F + c2) = o;
}

extern "C" void kernel_launch(void* const* d_in, const int* in_sizes, int n_in,
                              void* d_out, int out_size, void* d_ws, size_t ws_size,
                              hipStream_t stream) {
  const float* x     = (const float*)d_in[0];
  const int*   ei    = (const int*)d_in[1];
  const float* ew    = (const float*)d_in[2];
  const float* W1    = (const float*)d_in[3];
  const float* b1    = (const float*)d_in[4];
  const float* W2    = (const float*)d_in[5];
  const float* b2    = (const float*)d_in[6];
  const float* gamma = (const float*)d_in[7];
  const float* beta  = (const float*)d_in[8];
  float* out = (float*)d_out;

  const int D = 128, H = 256;
  const int N = in_sizes[0] / D;       // 50000
  const int E = in_sizes[2];           // 800000
  const int* src = ei;
  const int* dst = ei + E;

  // workspace carve-up (256B aligned).
  // head/next are dead after k_walk_fill; ax aliases them to keep footprint
  // within the bounds the previous (passing) rounds used (~110 MB).
  char* p = (char*)d_ws;
  auto carve = [&](size_t bytes) -> void* {
    void* r = (void*)p;
    p += (bytes + 255) & ~(size_t)255;
    return r;
  };
  float* dinv    = (float*)carve((size_t)N * 4);
  int*   cnt     = (int*)  carve((size_t)N * 4);
  int*   row_ptr = (int*)  carve((size_t)N * 4);
  int*   bsum    = (int*)  carve(TPB * 4);
  int*   bscan   = (int*)  carve(TPB * 4);
  int2*  csr     = (int2*) carve((size_t)E * 8);
  size_t listBytes = ((size_t)N * 4 + 255 & ~(size_t)255) + ((size_t)E * 4 + 255 & ~(size_t)255);
  size_t axBytes   = (size_t)N * D * 4;
  char*  unionA  = (char*)carve(listBytes > axBytes ? listBytes : axBytes);
  int*   head    = (int*)unionA;
  int*   next    = (int*)(unionA + (((size_t)N * 4 + 255) & ~(size_t)255));
  float* ax      = (float*)unionA;                    // aliases head/next (dead)
  float* out1    = (float*)carve((size_t)N * H * 4);  // relu(ax@W1+b1) [N,256]
  float* h2      = (float*)carve((size_t)N * D * 4);  // out1@W2      [N,128]

  const int gN = (N + TPB - 1) / TPB;   // 196
  const int gE = (E + TPB - 1) / TPB;

  // graph build: linked list -> walks -> scan -> fill
  k_head_init<<<gN, TPB, 0, stream>>>(head, N);
  k_link<<<gE, TPB, 0, stream>>>(dst, head, next, E);
  k_walk_deg<<<gN, TPB, 0, stream>>>(head, next, ew, dinv, cnt, N);
  k_block_reduce<<<gN, TPB, 0, stream>>>(cnt, bsum, N);
  k_scan_bsums<<<1, TPB, 0, stream>>>(bsum, bscan, gN);
  k_block_scan<<<gN, TPB, 0, stream>>>(cnt, bscan, row_ptr, N);
  k_walk_fill<<<gN, TPB, 0, stream>>>(head, next, src, ew, dinv, row_ptr, csr, N);

  // layer 1: aggregate-first, then fused GEMM+bias+relu
  k_agg_x<<<(N + 3) / 4, TPB, 0, stream>>>(x, dinv, row_ptr, cnt, csr, ax, N);
  dim3 g1(H / 64, (N + 63) / 64);
  k_gemm<<<g1, TPB, 0, stream>>>(ax, W1, out1, b1, 1, N, D, H);

  // layer 2: transform-first, then fused agg+bias+LN
  dim3 g2(D / 64, (N + 63) / 64);
  k_gemm<<<g2, TPB, 0, stream>>>(out1, W2, h2, nullptr, 0, N, H, D);
  k_agg2_ln<<<(N + 3) / 4, TPB, 0, stream>>>(h2, dinv, row_ptr, cnt, csr,
                                             b2, gamma, beta, out, N);
}

// Round 4
// 250.150 us; speedup vs baseline: 1.8890x; 1.3478x over previous
//
#include <hip/hip_runtime.h>

// ---------------------------------------------------------------------------
// 2-layer GCN + LayerNorm on MI355X (gfx950), bf16 MFMA GEMMs.
//   Graph build via per-dst linked list (1 atomic/edge), list walks, scan.
//   Layer 1 aggregate-first:  ax = A_norm @ x_bf16   -> out1 = relu(ax@W1+b1)
//   Layer 2 transform-first:  h2 = out1 @ W2 (bf16)  -> out = LN(agg(h2)+b2)
//   GEMMs: no-LDS direct-global mfma_f32_16x16x32_bf16; W pre-transposed bf16.
// ---------------------------------------------------------------------------

#define TPB 256

typedef __bf16 bf16;
typedef __bf16 bf16x2 __attribute__((ext_vector_type(2)));
typedef __bf16 bf16x4 __attribute__((ext_vector_type(4)));
typedef __bf16 bf16x8 __attribute__((ext_vector_type(8)));
typedef float  f32x4  __attribute__((ext_vector_type(4)));

__global__ void k_head_init(int* head, int N) {
  int i = blockIdx.x * TPB + threadIdx.x;
  if (i < N) head[i] = -1;
}

__global__ void k_link(const int* __restrict__ dst, int* head,
                       int* __restrict__ next, int E) {
  int e = blockIdx.x * TPB + threadIdx.x;
  if (e < E) next[e] = atomicExch(&head[dst[e]], e);
}

__global__ void k_walk_deg(const int* __restrict__ head, const int* __restrict__ next,
                           const float* __restrict__ ew, float* __restrict__ dinv,
                           int* __restrict__ cnt, int N) {
  int i = blockIdx.x * TPB + threadIdx.x;
  if (i >= N) return;
  float d = 1.0f;   // self-loop weight
  int c = 0;
  int h = head[i];
  while (h >= 0) {
    d += ew[h];
    ++c;
    h = next[h];
  }
  dinv[i] = rsqrtf(d);
  cnt[i] = c;
}

// ---- exclusive scan of cnt[N] ---------------------------------------------
__global__ void k_block_reduce(const int* __restrict__ cnt, int* bsum, int N) {
  __shared__ int sm[TPB];
  int i = blockIdx.x * TPB + threadIdx.x;
  sm[threadIdx.x] = (i < N) ? cnt[i] : 0;
  __syncthreads();
  for (int s = TPB / 2; s > 0; s >>= 1) {
    if (threadIdx.x < s) sm[threadIdx.x] += sm[threadIdx.x + s];
    __syncthreads();
  }
  if (threadIdx.x == 0) bsum[blockIdx.x] = sm[0];
}

__global__ void k_scan_bsums(const int* __restrict__ bsum, int* bscan, int nb) {
  __shared__ int sm[TPB];
  int t = threadIdx.x;
  int v = (t < nb) ? bsum[t] : 0;
  sm[t] = v;
  __syncthreads();
  for (int off = 1; off < TPB; off <<= 1) {
    int add = (t >= off) ? sm[t - off] : 0;
    __syncthreads();
    sm[t] += add;
    __syncthreads();
  }
  if (t < nb) bscan[t] = sm[t] - v;   // exclusive
}

__global__ void k_block_scan(const int* __restrict__ cnt, const int* __restrict__ bscan,
                             int* row_ptr, int N) {
  __shared__ int sm[TPB];
  int t = threadIdx.x;
  int i = blockIdx.x * TPB + t;
  int v = (i < N) ? cnt[i] : 0;
  sm[t] = v;
  __syncthreads();
  for (int off = 1; off < TPB; off <<= 1) {
    int add = (t >= off) ? sm[t - off] : 0;
    __syncthreads();
    sm[t] += add;
    __syncthreads();
  }
  if (i < N) row_ptr[i] = bscan[blockIdx.x] + sm[t] - v;
}

__global__ void k_walk_fill(const int* __restrict__ head, const int* __restrict__ next,
                            const int* __restrict__ src, const float* __restrict__ ew,
                            const float* __restrict__ dinv,
                            const int* __restrict__ row_ptr,
                            int2* __restrict__ csr, int N) {
  int i = blockIdx.x * TPB + threadIdx.x;
  if (i >= N) return;
  float di = dinv[i];
  int pos = row_ptr[i];
  int h = head[i];
  while (h >= 0) {
    int s = src[h];
    float nrm = dinv[s] * ew[h] * di;
    csr[pos++] = make_int2(s, __float_as_int(nrm));
    h = next[h];
  }
}

// ---- fp32 -> bf16 (vectorized, n4 = n/4) ----------------------------------
__global__ void k_cvt(const float* __restrict__ in, bf16* __restrict__ out, int n4) {
  int i = blockIdx.x * TPB + threadIdx.x;
  if (i < n4) {
    float4 v = reinterpret_cast<const float4*>(in)[i];
    bf16x4 o;
    o.x = (bf16)v.x; o.y = (bf16)v.y; o.z = (bf16)v.z; o.w = (bf16)v.w;
    reinterpret_cast<bf16x4*>(out)[i] = o;
  }
}

// ---- transpose+cast both weight matrices: W[K][NC] fp32 -> WT[NC][K] bf16 -
__global__ void k_cvtT2(const float* __restrict__ W1, bf16* __restrict__ W1T,
                        const float* __restrict__ W2, bf16* __restrict__ W2T,
                        int n1 /*=K1*NC1*/, int NC1, int K1,
                        int n2 /*=K2*NC2*/, int NC2, int K2) {
  int i = blockIdx.x * TPB + threadIdx.x;
  if (i < n1) {
    int r = i / NC1, c = i % NC1;
    W1T[(size_t)c * K1 + r] = (bf16)W1[i];
  }
  int j = i - n1;
  if (j >= 0 && j < n2) {
    int r = j / NC2, c = j % NC2;
    W2T[(size_t)c * K2 + r] = (bf16)W2[j];
  }
}

// ---- bf16 MFMA GEMM, no LDS: C[M,NC] = A[M,K] @ BT[NC,K]^T (+bias,+relu) --
// Block: 256 thr / 4 waves; BM=128 (wave w: rows 32w..32w+31), BN=64.
// Frag layout (16x16x32): elem j of lane l -> k = 8*(l>>4)+j, m/n = l&15.
// C/D: col = l&15, row = 4*(l>>4)+reg  [m89-verified].
__global__ __launch_bounds__(256) void k_gemm_mfma(
    const bf16* __restrict__ A, const bf16* __restrict__ BT,
    const float* __restrict__ bias, int relu, int M, int K, int NC,
    bf16* __restrict__ Cb, float* __restrict__ Cf) {
  const int l = threadIdx.x & 63, w = threadIdx.x >> 6;
  const int c = l & 15, g = l >> 4;
  const int m0 = blockIdx.x * 128 + w * 32;
  const int n0 = blockIdx.y * 64;

  int ra0 = m0 + c;       if (ra0 >= M) ra0 = M - 1;
  int ra1 = m0 + 16 + c;  if (ra1 >= M) ra1 = M - 1;
  const bf16* pa0 = A + (size_t)ra0 * K + g * 8;
  const bf16* pa1 = A + (size_t)ra1 * K + g * 8;
  const bf16* pb0 = BT + (size_t)(n0 + c) * K + g * 8;

  f32x4 acc[2][4] = {};
  for (int k0 = 0; k0 < K; k0 += 32) {
    bf16x8 a0 = *reinterpret_cast<const bf16x8*>(pa0 + k0);
    bf16x8 a1 = *reinterpret_cast<const bf16x8*>(pa1 + k0);
    bf16x8 b0 = *reinterpret_cast<const bf16x8*>(pb0 + k0);
    bf16x8 b1 = *reinterpret_cast<const bf16x8*>(pb0 + (size_t)16 * K + k0);
    bf16x8 b2 = *reinterpret_cast<const bf16x8*>(pb0 + (size_t)32 * K + k0);
    bf16x8 b3 = *reinterpret_cast<const bf16x8*>(pb0 + (size_t)48 * K + k0);
    acc[0][0] = __builtin_amdgcn_mfma_f32_16x16x32_bf16(a0, b0, acc[0][0], 0, 0, 0);
    acc[1][0] = __builtin_amdgcn_mfma_f32_16x16x32_bf16(a1, b0, acc[1][0], 0, 0, 0);
    acc[0][1] = __builtin_amdgcn_mfma_f32_16x16x32_bf16(a0, b1, acc[0][1], 0, 0, 0);
    acc[1][1] = __builtin_amdgcn_mfma_f32_16x16x32_bf16(a1, b1, acc[1][1], 0, 0, 0);
    acc[0][2] = __builtin_amdgcn_mfma_f32_16x16x32_bf16(a0, b2, acc[0][2], 0, 0, 0);
    acc[1][2] = __builtin_amdgcn_mfma_f32_16x16x32_bf16(a1, b2, acc[1][2], 0, 0, 0);
    acc[0][3] = __builtin_amdgcn_mfma_f32_16x16x32_bf16(a0, b3, acc[0][3], 0, 0, 0);
    acc[1][3] = __builtin_amdgcn_mfma_f32_16x16x32_bf16(a1, b3, acc[1][3], 0, 0, 0);
  }

#pragma unroll
  for (int mi = 0; mi < 2; ++mi) {
    int rbase = m0 + mi * 16 + g * 4;
#pragma unroll
    for (int ni = 0; ni < 4; ++ni) {
      int col = n0 + ni * 16 + c;
      float bv = bias ? bias[col] : 0.0f;
      f32x4 v = acc[mi][ni];
#pragma unroll
      for (int r = 0; r < 4; ++r) {
        int row = rbase + r;
        if (row < M) {
          float o = v[r] + bv;
          if (relu) o = fmaxf(o, 0.0f);
          if (Cb) Cb[(size_t)row * NC + col] = (bf16)o;
          else    Cf[(size_t)row * NC + col] = o;
        }
      }
    }
  }
}

// ---- aggregation on bf16 rows, F=128, one wave/node; bf16 out (layer 1) ---
__global__ __launch_bounds__(256) void k_agg_x(
    const bf16* __restrict__ h, const float* __restrict__ dinv,
    const int* __restrict__ row_ptr, const int* __restrict__ cnt,
    const int2* __restrict__ csr, bf16* __restrict__ out, int N) {
  const int F = 128;
  int wid = threadIdx.x >> 6, lane = threadIdx.x & 63;
  int node = blockIdx.x * 4 + wid;
  if (node >= N) return;
  float di = dinv[node];
  float sw = di * di;
  int c2 = lane << 1;
  bf16x2 hv = *reinterpret_cast<const bf16x2*>(h + (size_t)node * F + c2);
  float ax = sw * (float)hv.x, ay = sw * (float)hv.y;
  const int2* cp = csr + row_ptr[node];
  int n = cnt[node];
  int j = 0;
  for (; j + 4 <= n; j += 4) {
    int2 e0 = cp[j], e1 = cp[j + 1], e2 = cp[j + 2], e3 = cp[j + 3];
    bf16x2 v0 = *reinterpret_cast<const bf16x2*>(h + (size_t)e0.x * F + c2);
    bf16x2 v1 = *reinterpret_cast<const bf16x2*>(h + (size_t)e1.x * F + c2);
    bf16x2 v2 = *reinterpret_cast<const bf16x2*>(h + (size_t)e2.x * F + c2);
    bf16x2 v3 = *reinterpret_cast<const bf16x2*>(h + (size_t)e3.x * F + c2);
    float w0 = __int_as_float(e0.y), w1 = __int_as_float(e1.y);
    float w2 = __int_as_float(e2.y), w3 = __int_as_float(e3.y);
    ax += w0 * (float)v0.x + w1 * (float)v1.x + w2 * (float)v2.x + w3 * (float)v3.x;
    ay += w0 * (float)v0.y + w1 * (float)v1.y + w2 * (float)v2.y + w3 * (float)v3.y;
  }
  for (; j < n; ++j) {
    int2 e = cp[j];
    float w = __int_as_float(e.y);
    bf16x2 v = *reinterpret_cast<const bf16x2*>(h + (size_t)e.x * F + c2);
    ax += w * (float)v.x; ay += w * (float)v.y;
  }
  bf16x2 o; o.x = (bf16)ax; o.y = (bf16)ay;
  *reinterpret_cast<bf16x2*>(out + (size_t)node * F + c2) = o;
}

// ---- aggregation layer 2 (bf16 in) + bias + LayerNorm, fp32 out -----------
__global__ __launch_bounds__(256) void k_agg2_ln(
    const bf16* __restrict__ h, const float* __restrict__ dinv,
    const int* __restrict__ row_ptr, const int* __restrict__ cnt,
    const int2* __restrict__ csr, const float* __restrict__ b2,
    const float* __restrict__ gamma, const float* __restrict__ beta,
    float* __restrict__ out, int N) {
  const int F = 128;
  int wid = threadIdx.x >> 6, lane = threadIdx.x & 63;
  int node = blockIdx.x * 4 + wid;
  if (node >= N) return;
  float di = dinv[node];
  float sw = di * di;
  int c2 = lane << 1;
  float2 bb = *reinterpret_cast<const float2*>(b2 + c2);
  bf16x2 hv = *reinterpret_cast<const bf16x2*>(h + (size_t)node * F + c2);
  float ax = bb.x + sw * (float)hv.x, ay = bb.y + sw * (float)hv.y;
  const int2* cp = csr + row_ptr[node];
  int n = cnt[node];
  int j = 0;
  for (; j + 4 <= n; j += 4) {
    int2 e0 = cp[j], e1 = cp[j + 1], e2 = cp[j + 2], e3 = cp[j + 3];
    bf16x2 v0 = *reinterpret_cast<const bf16x2*>(h + (size_t)e0.x * F + c2);
    bf16x2 v1 = *reinterpret_cast<const bf16x2*>(h + (size_t)e1.x * F + c2);
    bf16x2 v2 = *reinterpret_cast<const bf16x2*>(h + (size_t)e2.x * F + c2);
    bf16x2 v3 = *reinterpret_cast<const bf16x2*>(h + (size_t)e3.x * F + c2);
    float w0 = __int_as_float(e0.y), w1 = __int_as_float(e1.y);
    float w2 = __int_as_float(e2.y), w3 = __int_as_float(e3.y);
    ax += w0 * (float)v0.x + w1 * (float)v1.x + w2 * (float)v2.x + w3 * (float)v3.x;
    ay += w0 * (float)v0.y + w1 * (float)v1.y + w2 * (float)v2.y + w3 * (float)v3.y;
  }
  for (; j < n; ++j) {
    int2 e = cp[j];
    float w = __int_as_float(e.y);
    bf16x2 v = *reinterpret_cast<const bf16x2*>(h + (size_t)e.x * F + c2);
    ax += w * (float)v.x; ay += w * (float)v.y;
  }
  // LayerNorm across the wave (128 values = 64 lanes x 2)
  float s  = ax + ay;
  float ss = ax * ax + ay * ay;
  for (int m = 32; m > 0; m >>= 1) {
    s  += __shfl_xor(s, m, 64);
    ss += __shfl_xor(ss, m, 64);
  }
  float mu  = s * (1.0f / 128.0f);
  float var = ss * (1.0f / 128.0f) - mu * mu;
  float inv = rsqrtf(var + 1e-5f);
  float2 g  = *reinterpret_cast<const float2*>(gamma + c2);
  float2 be = *reinterpret_cast<const float2*>(beta + c2);
  float2 o;
  o.x = (ax - mu) * inv * g.x + be.x;
  o.y = (ay - mu) * inv * g.y + be.y;
  *reinterpret_cast<float2*>(out + (size_t)node * F + c2) = o;
}

extern "C" void kernel_launch(void* const* d_in, const int* in_sizes, int n_in,
                              void* d_out, int out_size, void* d_ws, size_t ws_size,
                              hipStream_t stream) {
  const float* x     = (const float*)d_in[0];
  const int*   ei    = (const int*)d_in[1];
  const float* ew    = (const float*)d_in[2];
  const float* W1    = (const float*)d_in[3];
  const float* b1    = (const float*)d_in[4];
  const float* W2    = (const float*)d_in[5];
  const float* b2    = (const float*)d_in[6];
  const float* gamma = (const float*)d_in[7];
  const float* beta  = (const float*)d_in[8];
  float* out = (float*)d_out;

  const int D = 128, H = 256;
  const int N = in_sizes[0] / D;       // 50000
  const int E = in_sizes[2];           // 800000
  const int* src = ei;
  const int* dst = ei + E;

  // workspace carve-up (256B aligned); ~75 MB total
  char* p = (char*)d_ws;
  auto carve = [&](size_t bytes) -> void* {
    void* r = (void*)p;
    p += (bytes + 255) & ~(size_t)255;
    return r;
  };
  float* dinv    = (float*)carve((size_t)N * 4);
  int*   cnt     = (int*)  carve((size_t)N * 4);
  int*   row_ptr = (int*)  carve((size_t)N * 4);
  int*   bsum    = (int*)  carve(TPB * 4);
  int*   bscan   = (int*)  carve(TPB * 4);
  int*   head    = (int*)  carve((size_t)N * 4);
  int*   next    = (int*)  carve((size_t)E * 4);
  int2*  csr     = (int2*) carve((size_t)E * 8);
  bf16*  x_bf    = (bf16*) carve((size_t)N * D * 2);   // x cast to bf16
  bf16*  axb     = (bf16*) carve((size_t)N * D * 2);   // A_norm @ x (bf16)
  bf16*  out1    = (bf16*) carve((size_t)N * H * 2);   // relu(ax@W1+b1) (bf16)
  bf16*  h2      = (bf16*) carve((size_t)N * D * 2);   // out1@W2 (bf16)
  bf16*  W1T     = (bf16*) carve((size_t)D * H * 2);   // W1^T [256][128]
  bf16*  W2T     = (bf16*) carve((size_t)H * D * 2);   // W2^T [128][256]

  const int gN = (N + TPB - 1) / TPB;
  const int gE = (E + TPB - 1) / TPB;

  // graph build: linked list -> walks -> scan -> fill
  k_head_init<<<gN, TPB, 0, stream>>>(head, N);
  k_link<<<gE, TPB, 0, stream>>>(dst, head, next, E);
  k_walk_deg<<<gN, TPB, 0, stream>>>(head, next, ew, dinv, cnt, N);
  k_block_reduce<<<gN, TPB, 0, stream>>>(cnt, bsum, N);
  k_scan_bsums<<<1, TPB, 0, stream>>>(bsum, bscan, gN);
  k_block_scan<<<gN, TPB, 0, stream>>>(cnt, bscan, row_ptr, N);
  k_walk_fill<<<gN, TPB, 0, stream>>>(head, next, src, ew, dinv, row_ptr, csr, N);

  // casts: x -> bf16, W1/W2 -> transposed bf16
  int n4 = N * D / 4;
  k_cvt<<<(n4 + TPB - 1) / TPB, TPB, 0, stream>>>(x, x_bf, n4);
  int nw = D * H;
  k_cvtT2<<<(2 * nw + TPB - 1) / TPB, TPB, 0, stream>>>(W1, W1T, W2, W2T,
                                                        nw, H, D, nw, D, H);

  // layer 1: aggregate-first, then MFMA GEMM + bias + relu (bf16 out)
  k_agg_x<<<(N + 3) / 4, TPB, 0, stream>>>(x_bf, dinv, row_ptr, cnt, csr, axb, N);
  dim3 g1((N + 127) / 128, H / 64);
  k_gemm_mfma<<<g1, TPB, 0, stream>>>(axb, W1T, b1, 1, N, D, H, out1, nullptr);

  // layer 2: MFMA GEMM (bf16 out), then agg + bias + LN (fp32 out)
  dim3 g2((N + 127) / 128, D / 64);
  k_gemm_mfma<<<g2, TPB, 0, stream>>>(out1, W2T, nullptr, 0, N, H, D, h2, nullptr);
  k_agg2_ln<<<(N + 3) / 4, TPB, 0, stream>>>(h2, dinv, row_ptr, cnt, csr,
                                             b2, gamma, beta, out, N);
}

// Round 5
// 239.285 us; speedup vs baseline: 1.9747x; 1.0454x over previous
//
#include <hip/hip_runtime.h>

// ---------------------------------------------------------------------------
// 2-layer GCN + LayerNorm on MI355X (gfx950), bf16 MFMA GEMMs.
//   Graph build via per-dst linked list (1 atomic/edge), fused walks+scan.
//   Layer 1 aggregate-first:  ax = A_norm @ x_bf16   -> out1 = relu(ax@W1+b1)
//   Layer 2 transform-first:  h2 = out1 @ W2 (bf16)  -> out = LN(agg(h2)+b2)
//   Aggregation: one wave/node, HALF-WAVE per edge (32 lanes x bf16x4 = 256B
//   row), 2 edges per memory instruction, 8-edge unroll.
// ---------------------------------------------------------------------------

#define TPB 256

typedef __bf16 bf16;
typedef __bf16 bf16x4 __attribute__((ext_vector_type(4)));
typedef __bf16 bf16x8 __attribute__((ext_vector_type(8)));
typedef float  f32x4  __attribute__((ext_vector_type(4)));

// ---- prep: head=-1, x->bf16 (float4 granules), W1^T, W2^T (bf16) ----------
__global__ void k_prep(const float* __restrict__ x, bf16* __restrict__ x_bf,
                       const float* __restrict__ W1, bf16* __restrict__ W1T,
                       const float* __restrict__ W2, bf16* __restrict__ W2T,
                       int* __restrict__ head, int N, int n4, int nw,
                       int D, int H) {
  int i = blockIdx.x * TPB + threadIdx.x;
  if (i < N) head[i] = -1;
  if (i < nw) {
    int r1 = i / H, c1 = i % H;          // W1 [D][H] -> W1T [H][D]
    W1T[(size_t)c1 * D + r1] = (bf16)W1[i];
    int r2 = i / D, c2 = i % D;          // W2 [H][D] -> W2T [D][H]
    W2T[(size_t)c2 * H + r2] = (bf16)W2[i];
  }
  if (i < n4) {
    float4 v = reinterpret_cast<const float4*>(x)[i];
    bf16x4 o;
    o.x = (bf16)v.x; o.y = (bf16)v.y; o.z = (bf16)v.z; o.w = (bf16)v.w;
    reinterpret_cast<bf16x4*>(x_bf)[i] = o;
  }
}

__global__ void k_link(const int* __restrict__ dst, int* head,
                       int* __restrict__ next, int E) {
  int e = blockIdx.x * TPB + threadIdx.x;
  if (e < E) next[e] = atomicExch(&head[dst[e]], e);
}

// walk list: deg = 1 + sum(ew) -> dinv, cnt; fused per-block reduce -> bsum
__global__ void k_walk_deg(const int* __restrict__ head, const int* __restrict__ next,
                           const float* __restrict__ ew, float* __restrict__ dinv,
                           int* __restrict__ cnt, int* __restrict__ bsum, int N) {
  __shared__ int sm[TPB];
  int i = blockIdx.x * TPB + threadIdx.x;
  int c = 0;
  if (i < N) {
    float d = 1.0f;   // self-loop weight
    int h = head[i];
    while (h >= 0) {
      d += ew[h];
      ++c;
      h = next[h];
    }
    dinv[i] = rsqrtf(d);
    cnt[i] = c;
  }
  sm[threadIdx.x] = c;
  __syncthreads();
  for (int s = TPB / 2; s > 0; s >>= 1) {
    if (threadIdx.x < s) sm[threadIdx.x] += sm[threadIdx.x + s];
    __syncthreads();
  }
  if (threadIdx.x == 0) bsum[blockIdx.x] = sm[0];
}

__global__ void k_scan_bsums(const int* __restrict__ bsum, int* bscan, int nb) {
  __shared__ int sm[TPB];
  int t = threadIdx.x;
  int v = (t < nb) ? bsum[t] : 0;
  sm[t] = v;
  __syncthreads();
  for (int off = 1; off < TPB; off <<= 1) {
    int add = (t >= off) ? sm[t - off] : 0;
    __syncthreads();
    sm[t] += add;
    __syncthreads();
  }
  if (t < nb) bscan[t] = sm[t] - v;   // exclusive
}

// in-block scan of cnt -> row_ptr, then walk list filling {src, norm}
__global__ void k_scan_fill(const int* __restrict__ cnt, const int* __restrict__ bscan,
                            const int* __restrict__ head, const int* __restrict__ next,
                            const int* __restrict__ src, const float* __restrict__ ew,
                            const float* __restrict__ dinv,
                            int* __restrict__ row_ptr, int2* __restrict__ csr, int N) {
  __shared__ int sm[TPB];
  int t = threadIdx.x;
  int i = blockIdx.x * TPB + t;
  int v = (i < N) ? cnt[i] : 0;
  sm[t] = v;
  __syncthreads();
  for (int off = 1; off < TPB; off <<= 1) {
    int add = (t >= off) ? sm[t - off] : 0;
    __syncthreads();
    sm[t] += add;
    __syncthreads();
  }
  if (i < N) {
    int pos = bscan[blockIdx.x] + sm[t] - v;
    row_ptr[i] = pos;
    float di = dinv[i];
    int h = head[i];
    while (h >= 0) {
      int s = src[h];
      csr[pos++] = make_int2(s, __float_as_int(dinv[s] * ew[h] * di));
      h = next[h];
    }
  }
}

// ---- bf16 MFMA GEMM, no LDS: C[M,NC] = A[M,K] @ BT[NC,K]^T (+bias,+relu) --
// Block: 256 thr / 4 waves; BM=128 (wave w: rows 32w..32w+31), BN=64.
// Frag layout (16x16x32): elem j of lane l -> k = 8*(l>>4)+j, m/n = l&15.
// C/D: col = l&15, row = 4*(l>>4)+reg  [m89-verified].
__global__ __launch_bounds__(256) void k_gemm_mfma(
    const bf16* __restrict__ A, const bf16* __restrict__ BT,
    const float* __restrict__ bias, int relu, int M, int K, int NC,
    bf16* __restrict__ Cb) {
  const int l = threadIdx.x & 63, w = threadIdx.x >> 6;
  const int c = l & 15, g = l >> 4;
  const int m0 = blockIdx.x * 128 + w * 32;
  const int n0 = blockIdx.y * 64;

  int ra0 = m0 + c;       if (ra0 >= M) ra0 = M - 1;
  int ra1 = m0 + 16 + c;  if (ra1 >= M) ra1 = M - 1;
  const bf16* pa0 = A + (size_t)ra0 * K + g * 8;
  const bf16* pa1 = A + (size_t)ra1 * K + g * 8;
  const bf16* pb0 = BT + (size_t)(n0 + c) * K + g * 8;

  f32x4 acc[2][4] = {};
  for (int k0 = 0; k0 < K; k0 += 32) {
    bf16x8 a0 = *reinterpret_cast<const bf16x8*>(pa0 + k0);
    bf16x8 a1 = *reinterpret_cast<const bf16x8*>(pa1 + k0);
    bf16x8 b0 = *reinterpret_cast<const bf16x8*>(pb0 + k0);
    bf16x8 b1 = *reinterpret_cast<const bf16x8*>(pb0 + (size_t)16 * K + k0);
    bf16x8 b2 = *reinterpret_cast<const bf16x8*>(pb0 + (size_t)32 * K + k0);
    bf16x8 b3 = *reinterpret_cast<const bf16x8*>(pb0 + (size_t)48 * K + k0);
    acc[0][0] = __builtin_amdgcn_mfma_f32_16x16x32_bf16(a0, b0, acc[0][0], 0, 0, 0);
    acc[1][0] = __builtin_amdgcn_mfma_f32_16x16x32_bf16(a1, b0, acc[1][0], 0, 0, 0);
    acc[0][1] = __builtin_amdgcn_mfma_f32_16x16x32_bf16(a0, b1, acc[0][1], 0, 0, 0);
    acc[1][1] = __builtin_amdgcn_mfma_f32_16x16x32_bf16(a1, b1, acc[1][1], 0, 0, 0);
    acc[0][2] = __builtin_amdgcn_mfma_f32_16x16x32_bf16(a0, b2, acc[0][2], 0, 0, 0);
    acc[1][2] = __builtin_amdgcn_mfma_f32_16x16x32_bf16(a1, b2, acc[1][2], 0, 0, 0);
    acc[0][3] = __builtin_amdgcn_mfma_f32_16x16x32_bf16(a0, b3, acc[0][3], 0, 0, 0);
    acc[1][3] = __builtin_amdgcn_mfma_f32_16x16x32_bf16(a1, b3, acc[1][3], 0, 0, 0);
  }

#pragma unroll
  for (int mi = 0; mi < 2; ++mi) {
    int rbase = m0 + mi * 16 + g * 4;
#pragma unroll
    for (int ni = 0; ni < 4; ++ni) {
      int col = n0 + ni * 16 + c;
      float bv = bias ? bias[col] : 0.0f;
      f32x4 v = acc[mi][ni];
#pragma unroll
      for (int r = 0; r < 4; ++r) {
        int row = rbase + r;
        if (row < M) {
          float o = v[r] + bv;
          if (relu) o = fmaxf(o, 0.0f);
          Cb[(size_t)row * NC + col] = (bf16)o;
        }
      }
    }
  }
}

// ---- agg layer 1: F=128 bf16 rows, wave/node, half-wave per edge ----------
__global__ __launch_bounds__(256) void k_agg_x(
    const bf16* __restrict__ h, const float* __restrict__ dinv,
    const int* __restrict__ row_ptr, const int* __restrict__ cnt,
    const int2* __restrict__ csr, bf16* __restrict__ out, int N) {
  const int F = 128;
  int wid = threadIdx.x >> 6, lane = threadIdx.x & 63;
  int node = blockIdx.x * 4 + wid;
  if (node >= N) return;
  int half = lane >> 5;
  int c4 = (lane & 31) << 2;
  float a0 = 0.f, a1 = 0.f, a2 = 0.f, a3 = 0.f;
  float di = dinv[node];
  if (half == 0) {
    float sw = di * di;
    bf16x4 hv = *reinterpret_cast<const bf16x4*>(h + (size_t)node * F + c4);
    a0 = sw * (float)hv.x; a1 = sw * (float)hv.y;
    a2 = sw * (float)hv.z; a3 = sw * (float)hv.w;
  }
  const int2* cp = csr + row_ptr[node];
  int n = cnt[node];
  int j = 0;
  for (; j + 8 <= n; j += 8) {
    int2 eA = cp[j + half];
    int2 eB = cp[j + 2 + half];
    int2 eC = cp[j + 4 + half];
    int2 eD = cp[j + 6 + half];
    bf16x4 vA = *reinterpret_cast<const bf16x4*>(h + (size_t)eA.x * F + c4);
    bf16x4 vB = *reinterpret_cast<const bf16x4*>(h + (size_t)eB.x * F + c4);
    bf16x4 vC = *reinterpret_cast<const bf16x4*>(h + (size_t)eC.x * F + c4);
    bf16x4 vD = *reinterpret_cast<const bf16x4*>(h + (size_t)eD.x * F + c4);
    float wA = __int_as_float(eA.y), wB = __int_as_float(eB.y);
    float wC = __int_as_float(eC.y), wD = __int_as_float(eD.y);
    a0 += wA * (float)vA.x + wB * (float)vB.x + wC * (float)vC.x + wD * (float)vD.x;
    a1 += wA * (float)vA.y + wB * (float)vB.y + wC * (float)vC.y + wD * (float)vD.y;
    a2 += wA * (float)vA.z + wB * (float)vB.z + wC * (float)vC.z + wD * (float)vD.z;
    a3 += wA * (float)vA.w + wB * (float)vB.w + wC * (float)vC.w + wD * (float)vD.w;
  }
  for (; j < n; j += 2) {
    int idx = j + half;
    int2 e = (idx < n) ? cp[idx] : make_int2(0, 0);
    bf16x4 v = *reinterpret_cast<const bf16x4*>(h + (size_t)e.x * F + c4);
    float w = __int_as_float(e.y);
    a0 += w * (float)v.x; a1 += w * (float)v.y;
    a2 += w * (float)v.z; a3 += w * (float)v.w;
  }
  a0 += __shfl_xor(a0, 32, 64);
  a1 += __shfl_xor(a1, 32, 64);
  a2 += __shfl_xor(a2, 32, 64);
  a3 += __shfl_xor(a3, 32, 64);
  if (half == 0) {
    bf16x4 o;
    o.x = (bf16)a0; o.y = (bf16)a1; o.z = (bf16)a2; o.w = (bf16)a3;
    *reinterpret_cast<bf16x4*>(out + (size_t)node * F + c4) = o;
  }
}

// ---- agg layer 2 + bias + LayerNorm: half-wave per edge, fp32 out ---------
__global__ __launch_bounds__(256) void k_agg2_ln(
    const bf16* __restrict__ h, const float* __restrict__ dinv,
    const int* __restrict__ row_ptr, const int* __restrict__ cnt,
    const int2* __restrict__ csr, const float* __restrict__ b2,
    const float* __restrict__ gamma, const float* __restrict__ beta,
    float* __restrict__ out, int N) {
  const int F = 128;
  int wid = threadIdx.x >> 6, lane = threadIdx.x & 63;
  int node = blockIdx.x * 4 + wid;
  if (node >= N) return;
  int half = lane >> 5;
  int c4 = (lane & 31) << 2;
  float a0 = 0.f, a1 = 0.f, a2 = 0.f, a3 = 0.f;
  float di = dinv[node];
  if (half == 0) {
    float sw = di * di;
    float4 bb = *reinterpret_cast<const float4*>(b2 + c4);
    bf16x4 hv = *reinterpret_cast<const bf16x4*>(h + (size_t)node * F + c4);
    a0 = bb.x + sw * (float)hv.x; a1 = bb.y + sw * (float)hv.y;
    a2 = bb.z + sw * (float)hv.z; a3 = bb.w + sw * (float)hv.w;
  }
  const int2* cp = csr + row_ptr[node];
  int n = cnt[node];
  int j = 0;
  for (; j + 8 <= n; j += 8) {
    int2 eA = cp[j + half];
    int2 eB = cp[j + 2 + half];
    int2 eC = cp[j + 4 + half];
    int2 eD = cp[j + 6 + half];
    bf16x4 vA = *reinterpret_cast<const bf16x4*>(h + (size_t)eA.x * F + c4);
    bf16x4 vB = *reinterpret_cast<const bf16x4*>(h + (size_t)eB.x * F + c4);
    bf16x4 vC = *reinterpret_cast<const bf16x4*>(h + (size_t)eC.x * F + c4);
    bf16x4 vD = *reinterpret_cast<const bf16x4*>(h + (size_t)eD.x * F + c4);
    float wA = __int_as_float(eA.y), wB = __int_as_float(eB.y);
    float wC = __int_as_float(eC.y), wD = __int_as_float(eD.y);
    a0 += wA * (float)vA.x + wB * (float)vB.x + wC * (float)vC.x + wD * (float)vD.x;
    a1 += wA * (float)vA.y + wB * (float)vB.y + wC * (float)vC.y + wD * (float)vD.y;
    a2 += wA * (float)vA.z + wB * (float)vB.z + wC * (float)vC.z + wD * (float)vD.z;
    a3 += wA * (float)vA.w + wB * (float)vB.w + wC * (float)vC.w + wD * (float)vD.w;
  }
  for (; j < n; j += 2) {
    int idx = j + half;
    int2 e = (idx < n) ? cp[idx] : make_int2(0, 0);
    bf16x4 v = *reinterpret_cast<const bf16x4*>(h + (size_t)e.x * F + c4);
    float w = __int_as_float(e.y);
    a0 += w * (float)v.x; a1 += w * (float)v.y;
    a2 += w * (float)v.z; a3 += w * (float)v.w;
  }
  a0 += __shfl_xor(a0, 32, 64);
  a1 += __shfl_xor(a1, 32, 64);
  a2 += __shfl_xor(a2, 32, 64);
  a3 += __shfl_xor(a3, 32, 64);
  // LayerNorm: each lane (both halves duplicated) holds 4 cols
  float s  = a0 + a1 + a2 + a3;
  float ss = a0 * a0 + a1 * a1 + a2 * a2 + a3 * a3;
  for (int m = 16; m > 0; m >>= 1) {
    s  += __shfl_xor(s, m, 64);
    ss += __shfl_xor(ss, m, 64);
  }
  float mu  = s * (1.0f / 128.0f);
  float var = ss * (1.0f / 128.0f) - mu * mu;
  float inv = rsqrtf(var + 1e-5f);
  if (half == 0) {
    float4 g  = *reinterpret_cast<const float4*>(gamma + c4);
    float4 be = *reinterpret_cast<const float4*>(beta + c4);
    float4 o;
    o.x = (a0 - mu) * inv * g.x + be.x;
    o.y = (a1 - mu) * inv * g.y + be.y;
    o.z = (a2 - mu) * inv * g.z + be.z;
    o.w = (a3 - mu) * inv * g.w + be.w;
    *reinterpret_cast<float4*>(out + (size_t)node * F + c4) = o;
  }
}

extern "C" void kernel_launch(void* const* d_in, const int* in_sizes, int n_in,
                              void* d_out, int out_size, void* d_ws, size_t ws_size,
                              hipStream_t stream) {
  const float* x     = (const float*)d_in[0];
  const int*   ei    = (const int*)d_in[1];
  const float* ew    = (const float*)d_in[2];
  const float* W1    = (const float*)d_in[3];
  const float* b1    = (const float*)d_in[4];
  const float* W2    = (const float*)d_in[5];
  const float* b2    = (const float*)d_in[6];
  const float* gamma = (const float*)d_in[7];
  const float* beta  = (const float*)d_in[8];
  float* out = (float*)d_out;

  const int D = 128, H = 256;
  const int N = in_sizes[0] / D;       // 50000
  const int E = in_sizes[2];           // 800000
  const int* src = ei;
  const int* dst = ei + E;

  // workspace carve-up (256B aligned)
  char* p = (char*)d_ws;
  auto carve = [&](size_t bytes) -> void* {
    void* r = (void*)p;
    p += (bytes + 255) & ~(size_t)255;
    return r;
  };
  float* dinv    = (float*)carve((size_t)N * 4);
  int*   cnt     = (int*)  carve((size_t)N * 4);
  int*   row_ptr = (int*)  carve((size_t)N * 4);
  int*   bsum    = (int*)  carve(TPB * 4);
  int*   bscan   = (int*)  carve(TPB * 4);
  int*   head    = (int*)  carve((size_t)N * 4);
  int*   next    = (int*)  carve((size_t)E * 4);
  int2*  csr     = (int2*) carve((size_t)E * 8);
  bf16*  x_bf    = (bf16*) carve((size_t)N * D * 2);
  bf16*  axb     = (bf16*) carve((size_t)N * D * 2);
  bf16*  out1    = (bf16*) carve((size_t)N * H * 2);
  bf16*  h2      = (bf16*) carve((size_t)N * D * 2);
  bf16*  W1T     = (bf16*) carve((size_t)D * H * 2);
  bf16*  W2T     = (bf16*) carve((size_t)H * D * 2);

  const int gN = (N + TPB - 1) / TPB;
  const int gE = (E + TPB - 1) / TPB;
  const int n4 = N * D / 4;
  const int nw = D * H;
  const int gP = (n4 + TPB - 1) / TPB;   // covers n4 > N > nw

  k_prep<<<gP, TPB, 0, stream>>>(x, x_bf, W1, W1T, W2, W2T, head, N, n4, nw, D, H);
  k_link<<<gE, TPB, 0, stream>>>(dst, head, next, E);
  k_walk_deg<<<gN, TPB, 0, stream>>>(head, next, ew, dinv, cnt, bsum, N);
  k_scan_bsums<<<1, TPB, 0, stream>>>(bsum, bscan, gN);
  k_scan_fill<<<gN, TPB, 0, stream>>>(cnt, bscan, head, next, src, ew, dinv,
                                      row_ptr, csr, N);

  // layer 1: aggregate-first, then MFMA GEMM + bias + relu (bf16 out)
  k_agg_x<<<(N + 3) / 4, TPB, 0, stream>>>(x_bf, dinv, row_ptr, cnt, csr, axb, N);
  dim3 g1((N + 127) / 128, H / 64);
  k_gemm_mfma<<<g1, TPB, 0, stream>>>(axb, W1T, b1, 1, N, D, H, out1);

  // layer 2: MFMA GEMM (bf16 out), then agg + bias + LN (fp32 out)
  dim3 g2((N + 127) / 128, D / 64);
  k_gemm_mfma<<<g2, TPB, 0, stream>>>(out1, W2T, nullptr, 0, N, H, D, h2);
  k_agg2_ln<<<(N + 3) / 4, TPB, 0, stream>>>(h2, dinv, row_ptr, cnt, csr,
                                             b2, gamma, beta, out, N);
}